// Round 1
// 1338.218 us; speedup vs baseline: 1.7685x; 1.7685x over previous
//
#include <hip/hip_runtime.h>

typedef unsigned short u16;
typedef unsigned int u32;

#define NTOK 144
#define CDIM 192
#define NHEADS 6
#define HDIM 32
#define NWIN 64
#define NB 30
#define NBLK (NB * NWIN)
#define SCALE 0.17677669529663687f

typedef __bf16 bf16x8 __attribute__((ext_vector_type(8)));
typedef float f32x4 __attribute__((ext_vector_type(4)));

__device__ __forceinline__ float bf2f(u16 u) {
    union { u32 i; float f; } v; v.i = ((u32)u) << 16; return v.f;
}
__device__ __forceinline__ u16 f2bf(float f) {
    union { float f; u32 i; } v; v.f = f;
    u32 r = v.i + 0x7FFFu + ((v.i >> 16) & 1u);   // RNE
    return (u16)(r >> 16);
}

// -------- dtype-robust scalar accessors (fm==1: buffers are fp32) --------
__device__ __forceinline__ float ld_s(const void* base, size_t idx, int fm) {
    return fm ? ((const float*)base)[idx] : bf2f(((const u16*)base)[idx]);
}
__device__ __forceinline__ void st_s(void* base, size_t idx, float v, int fm) {
    if (fm) ((float*)base)[idx] = v; else ((u16*)base)[idx] = f2bf(v);
}

// ---------------- LDS layout (u16 units, total 77312 u16 = 154,624 B) ----------------
// X  [144][200] @ 0      : x[window] as bf16, staged once per block (cols 0..191 used)
// W  [96][200]  @ 28800  : per-head qkv_w slice (rows: 32 q, 32 k, 32 v) — live B6..B1
// WP [192][40]  @ 28800  : per-head proj_w slice, overlays W after B1 (t1 done with W)
// R1 @ 48000 time-multiplexed: q[144][40]@48000 + k[144][40]@53760 (t1->t2)
//                              P[144][168]@48000                   (Pw->PV)
//                              O[144][40]@48000                    (Ow->t4)
// vT [32][160] @ 72192   : v^T, cols 144..159 zeroed at start, never overwritten
#define X_OFF  0
#define X_STR  200
#define W_OFF  28800
#define W_STR  200
#define WP_OFF 28800
#define WP_STR 40
#define QK_STR 40
#define R1_Q   48000
#define R1_K   53760
#define P_OFF  48000
#define P_STR  168
#define O_OFF  48000
#define O_STR  40
#define VT_OFF 72192
#define VT_STR 160
#define SM_TOT 77312

// -------- detector: bf16 vs fp32 input encoding --------
// Real bf16 N(0,0.02) data: no u16 has bf16-exponent >= 0x8E (|v|>=3e4).
// fp32 data read as u16 pairs: low halves have ~44% such patterns.
__global__ void detect_mode(const u16* __restrict__ w, int* __restrict__ flag) {
    __shared__ int cnt;
    if (threadIdx.x == 0) cnt = 0;
    __syncthreads();
    int h = 0;
    for (int i = threadIdx.x; i < 4096; i += 256) {
        int e = (w[i] >> 7) & 0xFF;
        if (e >= 0x8E) h++;
    }
    atomicAdd(&cnt, h);
    __syncthreads();
    if (threadIdx.x == 0) flag[0] = (cnt > 64) ? 1 : 0;
}

// -------- prologue: materialize bias_g[w][h][n][m] as canonical bf16 --------
__global__ void bias_gather(const void* __restrict__ table, const int* __restrict__ pos,
                            u16* __restrict__ bias_g, const int* __restrict__ mode) {
    const int fm = mode[0];
    int wh = blockIdx.x;            // 0..383
    int w = wh / NHEADS, h = wh % NHEADS;
    u16* o = bias_g + (size_t)wh * (NTOK * NTOK);
    for (int i = threadIdx.x; i < NTOK * NTOK; i += 256) {
        int idx = pos[i];
        size_t j = ((size_t)idx * NWIN + w) * NHEADS + h;
        o[i] = fm ? f2bf(((const float*)table)[j]) : ((const u16*)table)[j];
    }
}

// ---------------- main fused kernel: one block per (b,w) window ----------------
__global__ __launch_bounds__(576, 3)
void earth_attn(const void* __restrict__ x, const void* __restrict__ qkv_w,
                const void* __restrict__ qkv_b, const void* __restrict__ proj_w,
                const void* __restrict__ proj_b, const void* __restrict__ bias_table,
                const int* __restrict__ pos_index, const u16* __restrict__ bias_g,
                int use_bias_g, void* __restrict__ out, const int* __restrict__ mode) {
    __shared__ __align__(16) u16 sm[SM_TOT];

    const int fm   = mode[0];
    const int tid  = threadIdx.x;
    const int wv   = tid >> 6;       // 0..8  (16-row M-tile owner)
    const int lane = tid & 63;
    const int l15  = lane & 15;
    const int lq   = lane >> 4;      // 0..3

    // XCD-chunked swizzle + window-major remap:
    //  - each XCD gets a contiguous chunk of 240 blocks (8 w-values) -> bias_g/qkv_w L2-local
    //  - 30 consecutive blocks share w -> bias_g slice fetched ~once per XCD
    const int blk   = blockIdx.x;                       // 0..1919
    const int virt  = (blk & 7) * (NBLK / 8) + (blk >> 3);
    const int w     = virt / NB;                        // 0..63
    const int bwlin = (virt % NB) * NWIN + w;           // linear (b,w) index into x/out

    // P0: zero ALL of LDS (covers vT pad; converts any uncovered-read bug to finite)
    {
        uint4 z; z.x = z.y = z.z = z.w = 0u;
        for (int i = tid; i < SM_TOT / 8; i += 576) *(uint4*)&sm[i * 8] = z;
    }
    __syncthreads();

    // P1: stage x[window] -> X LDS as bf16 (convert ONCE; removes 6x global re-read)
    const size_t xbase = (size_t)bwlin * (NTOK * CDIM);
    if (fm) {
        const float* xs = (const float*)x + xbase;
        for (int i = tid; i < NTOK * CDIM / 4; i += 576) {      // 6912 = 12*576
            const float4 v = *(const float4*)(xs + i * 4);
            int r = i / 48, c = (i % 48) * 4;
            u16* d = &sm[X_OFF + r * X_STR + c];
            d[0] = f2bf(v.x); d[1] = f2bf(v.y); d[2] = f2bf(v.z); d[3] = f2bf(v.w);
        }
    } else {
        const u16* xs = (const u16*)x + xbase;
        for (int i = tid; i < NTOK * CDIM / 8; i += 576) {      // 3456 = 6*576
            int r = i / 24, c = (i % 24) * 8;
            *(uint4*)&sm[X_OFF + r * X_STR + c] = *(const uint4*)(xs + i * 8);
        }
    }

    const f32x4 fzero = {0.f, 0.f, 0.f, 0.f};
    f32x4 oacc[12];                  // out rows [wv*16..+15] x 192, fp32 (fused proj acc)
    for (int nt = 0; nt < 12; ++nt) oacc[nt] = fzero;

    const int hoffbase = 0;
    (void)hoffbase;

    __syncthreads();                                  // B0 (X staged)

    for (int h = 0; h < NHEADS; ++h) {
        const int hoff = h * HDIM;

        // ---- stage W: qkv_w head-slice (96 rows x 192 cols) -> LDS bf16, once per block ----
        // slice row r <-> global row (r>>5)*CDIM + hoff + (r&31)   (32 q, 32 k, 32 v)
        if (fm) {
            const float* ws = (const float*)qkv_w;
            for (int i = tid; i < 96 * CDIM / 4; i += 576) {    // 4608 = 8*576
                int r = i / 48, c = (i % 48) * 4;
                int grow = (r >> 5) * CDIM + hoff + (r & 31);
                const float4 v = *(const float4*)(ws + (size_t)grow * CDIM + c);
                u16* d = &sm[W_OFF + r * W_STR + c];
                d[0] = f2bf(v.x); d[1] = f2bf(v.y); d[2] = f2bf(v.z); d[3] = f2bf(v.w);
            }
        } else {
            const u16* ws = (const u16*)qkv_w;
            for (int i = tid; i < 96 * CDIM / 8; i += 576) {    // 2304 = 4*576
                int r = i / 24, c = (i % 24) * 8;
                int grow = (r >> 5) * CDIM + hoff + (r & 31);
                *(uint4*)&sm[W_OFF + r * W_STR + c] = *(const uint4*)(ws + (size_t)grow * CDIM + c);
            }
        }
        __syncthreads();                              // Bw (W staged before t1 reads)

        // ---- t1: qkv_h = x @ Wh^T  (M=144, N=96, K=192); A,B from LDS ----
        {
            f32x4 acc[6];
            for (int nt = 0; nt < 6; ++nt) acc[nt] = fzero;
#pragma unroll
            for (int kt = 0; kt < 6; ++kt) {
                bf16x8 a = *(const bf16x8*)&sm[X_OFF + (wv * 16 + l15) * X_STR + kt * 32 + lq * 8];
#pragma unroll
                for (int nt = 0; nt < 6; ++nt) {
                    bf16x8 bb = *(const bf16x8*)&sm[W_OFF + (nt * 16 + l15) * W_STR + kt * 32 + lq * 8];
                    acc[nt] = __builtin_amdgcn_mfma_f32_16x16x32_bf16(a, bb, acc[nt], 0, 0, 0);
                }
            }
            // scatter to q (scaled) / k / v^T as bf16; s is uniform per nt
#pragma unroll
            for (int nt = 0; nt < 6; ++nt) {
                int col = nt * 16 + l15;         // 0..95
                int s = col >> 5, d = col & 31;
                float bias = ld_s(qkv_b, s * CDIM + hoff + d, fm);
#pragma unroll
                for (int r = 0; r < 4; ++r) {
                    int row = wv * 16 + lq * 4 + r;
                    float v = acc[nt][r] + bias;
                    if (s == 0)      sm[R1_Q + row * QK_STR + d] = f2bf(v * SCALE);
                    else if (s == 1) sm[R1_K + row * QK_STR + d] = f2bf(v);
                    else             sm[VT_OFF + d * VT_STR + row] = f2bf(v);
                }
            }
        }
        __syncthreads();                              // B1 (W region dead from here)

        // ---- stage WP: proj_w head-slice (192 rows x 32 cols) -> LDS, overlays W region.
        //      Safe: t1 reads of W finished at B1; WP consumed in t4 (after B2..B5). ----
        if (fm) {
            const float* ps = (const float*)proj_w;
            for (int i = tid; i < 192 * 32 / 4; i += 576) {     // 1536
                int r = i >> 3, c = (i & 7) * 4;
                const float4 v = *(const float4*)(ps + (size_t)r * CDIM + hoff + c);
                u16* d = &sm[WP_OFF + r * WP_STR + c];
                d[0] = f2bf(v.x); d[1] = f2bf(v.y); d[2] = f2bf(v.z); d[3] = f2bf(v.w);
            }
        } else {
            const u16* ps = (const u16*)proj_w;
            for (int i = tid; i < 192 * 32 / 8; i += 576) {     // 768
                int r = i >> 2, c = (i & 3) * 8;
                *(uint4*)&sm[WP_OFF + r * WP_STR + c] = *(const uint4*)(ps + (size_t)r * CDIM + hoff + c);
            }
        }

        // ---- t2: S = q @ k^T + bias; softmax (all in registers) ----
        f32x4 sacc[9];
        {
            bf16x8 a = *(const bf16x8*)&sm[R1_Q + (wv * 16 + l15) * QK_STR + lq * 8];
#pragma unroll
            for (int nt = 0; nt < 9; ++nt) {
                bf16x8 bb = *(const bf16x8*)&sm[R1_K + (nt * 16 + l15) * QK_STR + lq * 8];
                sacc[nt] = __builtin_amdgcn_mfma_f32_16x16x32_bf16(a, bb, fzero, 0, 0, 0);
            }
            const u16* bg = bias_g + (size_t)(w * NHEADS + h) * (NTOK * NTOK);
#pragma unroll
            for (int nt = 0; nt < 9; ++nt) {
                int col = nt * 16 + l15;
#pragma unroll
                for (int r = 0; r < 4; ++r) {
                    int row = wv * 16 + lq * 4 + r;
                    float bv;
                    if (use_bias_g) bv = bf2f(bg[row * NTOK + col]);
                    else {
                        int idx = pos_index[row * NTOK + col];
                        bv = ld_s(bias_table, ((size_t)idx * NWIN + w) * NHEADS + h, fm);
                    }
                    sacc[nt][r] += bv;
                }
            }
#pragma unroll
            for (int r = 0; r < 4; ++r) {
                float m = -1e30f;
                for (int nt = 0; nt < 9; ++nt) m = fmaxf(m, sacc[nt][r]);
                for (int d = 1; d < 16; d <<= 1) m = fmaxf(m, __shfl_xor(m, d, 64));
                float s = 0.f;
                for (int nt = 0; nt < 9; ++nt) {
                    float e = __expf(sacc[nt][r] - m);
                    sacc[nt][r] = e; s += e;
                }
                for (int d = 1; d < 16; d <<= 1) s += __shfl_xor(s, d, 64);
                float inv = 1.0f / s;
                for (int nt = 0; nt < 9; ++nt) sacc[nt][r] *= inv;
            }
        }
        __syncthreads();                              // B2 (q/k dead; P overwrites them)

        // ---- P write: bf16 [144][168], cols 144..159 re-zeroed (K-pad) ----
#pragma unroll
        for (int r = 0; r < 4; ++r) {
            int row = wv * 16 + lq * 4 + r;
#pragma unroll
            for (int nt = 0; nt < 9; ++nt)
                sm[P_OFF + row * P_STR + nt * 16 + l15] = f2bf(sacc[nt][r]);
            sm[P_OFF + row * P_STR + 144 + l15] = 0;
        }
        __syncthreads();                              // B3

        // ---- t3: O_h = P @ v  (M=144, N=32, K=160 padded) ----
        f32x4 pv[2] = {fzero, fzero};
#pragma unroll
        for (int kt = 0; kt < 5; ++kt) {
            bf16x8 a = *(const bf16x8*)&sm[P_OFF + (wv * 16 + l15) * P_STR + kt * 32 + lq * 8];
#pragma unroll
            for (int dt = 0; dt < 2; ++dt) {
                bf16x8 bb = *(const bf16x8*)&sm[VT_OFF + (dt * 16 + l15) * VT_STR + kt * 32 + lq * 8];
                pv[dt] = __builtin_amdgcn_mfma_f32_16x16x32_bf16(a, bb, pv[dt], 0, 0, 0);
            }
        }
        __syncthreads();                              // B4 (P dead; O overwrites)

        // ---- O write (single bf16; O-scale ~0.03 so rounding ~6e-5 << threshold) ----
#pragma unroll
        for (int dt = 0; dt < 2; ++dt)
#pragma unroll
            for (int r = 0; r < 4; ++r) {
                int row = wv * 16 + lq * 4 + r, d = dt * 16 + l15;
                sm[O_OFF + row * O_STR + d] = f2bf(pv[dt][r]);
            }
        __syncthreads();                              // B5

        // ---- t4: out += O_h @ Pw_h^T  (M=144, N=192, K=32); A,B from LDS ----
        {
            bf16x8 a = *(const bf16x8*)&sm[O_OFF + (wv * 16 + l15) * O_STR + lq * 8];
#pragma unroll
            for (int nt = 0; nt < 12; ++nt) {
                bf16x8 bb = *(const bf16x8*)&sm[WP_OFF + (nt * 16 + l15) * WP_STR + lq * 8];
                oacc[nt] = __builtin_amdgcn_mfma_f32_16x16x32_bf16(a, bb, oacc[nt], 0, 0, 0);
            }
        }
        __syncthreads();                              // B6 (O/WP dead; next head overwrites)
    }

    // ---- epilogue: + proj_b, store (dtype per mode) ----
    const size_t obase = (size_t)bwlin * (NTOK * CDIM);
#pragma unroll
    for (int nt = 0; nt < 12; ++nt) {
        int col = nt * 16 + l15;
        float pb = ld_s(proj_b, col, fm);
#pragma unroll
        for (int r = 0; r < 4; ++r) {
            int row = wv * 16 + lq * 4 + r;
            st_s(out, obase + row * CDIM + col, oacc[nt][r] + pb, fm);
        }
    }
}

extern "C" void kernel_launch(void* const* d_in, const int* in_sizes, int n_in,
                              void* d_out, int out_size, void* d_ws, size_t ws_size,
                              hipStream_t stream) {
    const void* x          = d_in[0];
    const void* qkv_w      = d_in[1];
    const void* qkv_b      = d_in[2];
    const void* proj_w     = d_in[3];
    const void* proj_b     = d_in[4];
    const void* bias_table = d_in[5];
    const int*  pos_index  = (const int*)d_in[6];

    int*  mode_flag = (int*)d_ws;                       // ws[0..15]: mode flag
    u16*  bias_g    = (u16*)((char*)d_ws + 16);         // ws[16..]: gathered bias

    const size_t bias_g_bytes = (size_t)NWIN * NHEADS * NTOK * NTOK * sizeof(u16);
    int use_ws = (ws_size >= bias_g_bytes + 16) ? 1 : 0;

    detect_mode<<<dim3(1), dim3(256), 0, stream>>>((const u16*)qkv_w, mode_flag);
    if (use_ws)
        bias_gather<<<dim3(NWIN * NHEADS), dim3(256), 0, stream>>>(
            bias_table, pos_index, bias_g, mode_flag);
    earth_attn<<<dim3(NBLK), dim3(576), 0, stream>>>(
        x, qkv_w, qkv_b, proj_w, proj_b, bias_table, pos_index, bias_g, use_ws,
        d_out, mode_flag);
}